// Round 3
// baseline (893.383 us; speedup 1.0000x reference)
//
#include <hip/hip_runtime.h>
#include <math.h>

#define B_   16
#define S_   4096
#define I_   128
#define HD_  384
#define M_   256
#define K_   384   // M_+I_
#define EPS_ 1e-5f

// ---------------------------------------------------------------- K1: u_pre + BN(u)
__global__ __launch_bounds__(256) void k_upre(const float* __restrict__ x,
                                              const float* __restrict__ wu,
                                              const float* __restrict__ wub,
                                              const float* __restrict__ g_u,
                                              const float* __restrict__ b_u,
                                              const float* __restrict__ mu_u,
                                              const float* __restrict__ var_u,
                                              float* __restrict__ u_bn) {
    __shared__ float w[I_];
    int tid = threadIdx.x;
    if (tid < I_) w[tid] = wu[tid];
    __syncthreads();
    int row = blockIdx.x * 256 + tid;            // 0..65535
    const float4* xr = (const float4*)(x + (size_t)row * I_);
    const float4* w4 = (const float4*)w;
    float4 s4 = {0.f, 0.f, 0.f, 0.f};
    #pragma unroll
    for (int i = 0; i < I_ / 4; i++) {
        float4 xv = xr[i], wv = w4[i];
        s4.x += xv.x * wv.x; s4.y += xv.y * wv.y;
        s4.z += xv.z * wv.z; s4.w += xv.w * wv.w;
    }
    float s = (s4.x + s4.y) + (s4.z + s4.w) + wub[0];
    float rs = 1.0f / sqrtf(var_u[0] + EPS_);
    u_bn[row] = g_u[0] * (s - mu_u[0]) * rs + b_u[0];
}

// ---------------------------------------------------------------- K2: u-LIF (chunk 4, warm-up 128)
__global__ __launch_bounds__(256) void k_ulif(const float* __restrict__ u_bn,
                                              float* __restrict__ u_spk) {
    int b = blockIdx.x, tid = threadIdx.x;
    int chunk = blockIdx.y * 256 + tid;          // 0..1023
    int t0 = chunk * 4;
    int start = t0 - 128; if (start < 0) start = 0;
    const float* ub = u_bn + (size_t)b * S_;
    float v = 0.f;
    for (int t = start; t < t0 + 4; t++) {
        float xv = ub[t];
        v = v + (xv - v) * 0.5f;
        float sp = (v - 1.0f) >= 0.0f ? 1.0f : 0.0f;
        if (t >= t0) u_spk[(size_t)b * S_ + t] = sp;
        v = v * (1.0f - sp);
    }
}

// ---------------------------------------------------------------- K2b: compact sorted spike lists
__global__ __launch_bounds__(256) void k_compact(const float* __restrict__ u_spk,
                                                 int* __restrict__ spk_idx,
                                                 int* __restrict__ spk_cnt) {
    __shared__ int wcnt[4];
    __shared__ int base;
    int b = blockIdx.x, tid = threadIdx.x;
    int lane = tid & 63, w = tid >> 6;
    if (tid == 0) base = 0;
    __syncthreads();
    for (int r = 0; r < 16; r++) {
        int t = r * 256 + tid;
        bool f = u_spk[(size_t)b * S_ + t] > 0.5f;
        unsigned long long bal = __ballot(f);
        int pre = __popcll(bal & (((unsigned long long)1 << lane) - 1ull));
        if (lane == 0) wcnt[w] = __popcll(bal);
        __syncthreads();
        int off = base;
        for (int i = 0; i < w; i++) off += wcnt[i];
        if (f) spk_idx[(size_t)b * S_ + off + pre] = t;
        __syncthreads();
        if (tid == 0) base += wcnt[0] + wcnt[1] + wcnt[2] + wcnt[3];
        __syncthreads();
    }
    if (tid == 0) spk_cnt[b] = base;
}

// ---------------------------------------------------------------- K3: sparse conv + BN(m)  -> m_bn [B,M,S]
// Zero-padded H in LDS. acc[i] covers t = tid + 256*i. Per spike (scalar-uniform
// tau): up to 16 conflict-free ds_read_b32 + adds; tap groups provably in the
// zero pad are skipped via scalar branches.
__global__ __launch_bounds__(256) void k_conv(const float* __restrict__ H,
                                              const int* __restrict__ spk_idx,
                                              const int* __restrict__ spk_cnt,
                                              const float* __restrict__ g_m,
                                              const float* __restrict__ b_m,
                                              const float* __restrict__ mu_m,
                                              const float* __restrict__ var_m,
                                              float* __restrict__ m_bn) {
    __shared__ float Hpad[2 * S_];
    __shared__ int spk[S_];
    int bid = blockIdx.x;
    int b = bid >> 8, ch = bid & 255;
    int tid = threadIdx.x;
    float4* Hz = (float4*)Hpad;
    for (int i = tid; i < S_ / 4; i += 256) Hz[i] = make_float4(0.f, 0.f, 0.f, 0.f);
    const float4* Hv = (const float4*)(H + (size_t)ch * S_);
    float4* Hu = (float4*)(Hpad + S_);
    for (int i = tid; i < S_ / 4; i += 256) Hu[i] = Hv[i];
    int n = spk_cnt[b];
    const int* sl = spk_idx + (size_t)b * S_;
    for (int i = tid; i < n; i += 256) spk[i] = sl[i];
    __syncthreads();

    float acc[16];
    #pragma unroll
    for (int i = 0; i < 16; i++) acc[i] = 0.f;
    const float* base = Hpad + S_ + tid;
    int sw63 = __builtin_amdgcn_readfirstlane(tid | 63);   // wave max tid

    #pragma unroll 2
    for (int j = 0; j < n; j++) {
        int tau = __builtin_amdgcn_readfirstlane(spk[j]);
        const float* hp = base - tau;
        int d = tau - sw63;     // group g has any nonzero tap iff d <= 256*(4g+3)
        if (d <= 768) {
            acc[0] += hp[0];    acc[1] += hp[256];
            acc[2] += hp[512];  acc[3] += hp[768];
        }
        if (d <= 1792) {
            acc[4] += hp[1024]; acc[5] += hp[1280];
            acc[6] += hp[1536]; acc[7] += hp[1792];
        }
        if (d <= 2816) {
            acc[8] += hp[2048];  acc[9] += hp[2304];
            acc[10] += hp[2560]; acc[11] += hp[2816];
        }
        if (d <= 3840) {
            acc[12] += hp[3072]; acc[13] += hp[3328];
            acc[14] += hp[3584]; acc[15] += hp[3840];
        }
    }

    float g = g_m[ch], bb = b_m[ch], mu = mu_m[ch];
    float rs = 1.0f / sqrtf(var_m[ch] + EPS_);
    float* out = m_bn + ((size_t)b * M_ + ch) * S_;
    #pragma unroll
    for (int i = 0; i < 16; i++)
        out[tid + 256 * i] = g * (acc[i] - mu) * rs + bb;
}

// ---------------------------------------------------------------- K5: m-LIF (chunk 256, warm-up 128) -> m_s [B,S,M]
__global__ __launch_bounds__(256) void k_mlif(const float* __restrict__ m_bn,
                                              float* __restrict__ m_s) {
    int b = blockIdx.x;
    int ch = blockIdx.y * 64 + threadIdx.x;
    int c = blockIdx.z * 4 + threadIdx.y;        // 0..15
    int t0 = c * 256;
    int start = t0 - 128; if (start < 0) start = 0;
    const float* src = m_bn + ((size_t)b * M_ + ch) * S_;
    float v = 0.f;
    for (int t = start; t < t0 + 256; t += 4) {
        float4 xv = *(const float4*)(src + t);
        float xs[4] = {xv.x, xv.y, xv.z, xv.w};
        #pragma unroll
        for (int u = 0; u < 4; u++) {
            int t2 = t + u;
            v = v + (xs[u] - v) * 0.5f;
            float sp = (v - 1.0f) >= 0.0f ? 1.0f : 0.0f;
            if (t2 >= t0) m_s[((size_t)b * S_ + t2) * M_ + ch] = sp;
            v = v * (1.0f - sp);
        }
    }
}

// ---------------------------------------------------------------- K6: h GEMM (fp32) 128x128 tile, 8x8/thread
__global__ __launch_bounds__(256) void k_hgemm(const float* __restrict__ m_s,
                                               const float* __restrict__ x,
                                               const float* __restrict__ W,
                                               const float* __restrict__ Wb,
                                               const float* __restrict__ g_h,
                                               const float* __restrict__ b_h,
                                               const float* __restrict__ mu_h,
                                               const float* __restrict__ var_h,
                                               float* __restrict__ h_bn) {
    __shared__ float As[32 * 128];   // As[k][row]
    __shared__ float Bs[32 * 128];   // Bs[k][col]
    int tid = threadIdx.x;
    int row0 = blockIdx.x * 128, col0 = blockIdx.y * 128;
    int tx = tid & 15, ty = tid >> 4;          // micro-tile: 8 cols, 8 rows
    int lrow = tid & 127, half = tid >> 7;     // staging
    float acc[8][8] = {};

    for (int kt = 0; kt < 12; kt++) {
        int kbase = kt * 32 + half * 16;
        const float* Asrc;
        if (kt < 8) Asrc = m_s + (size_t)(row0 + lrow) * M_ + kbase;
        else        Asrc = x   + (size_t)(row0 + lrow) * I_ + (kbase - M_);
        const float* Bsrc = W + (size_t)(col0 + lrow) * K_ + kbase;
        #pragma unroll
        for (int i = 0; i < 4; i++) {
            float4 va = *(const float4*)(Asrc + i * 4);
            float4 vb = *(const float4*)(Bsrc + i * 4);
            int k = half * 16 + i * 4;
            As[(k + 0) * 128 + lrow] = va.x;
            As[(k + 1) * 128 + lrow] = va.y;
            As[(k + 2) * 128 + lrow] = va.z;
            As[(k + 3) * 128 + lrow] = va.w;
            Bs[(k + 0) * 128 + lrow] = vb.x;
            Bs[(k + 1) * 128 + lrow] = vb.y;
            Bs[(k + 2) * 128 + lrow] = vb.z;
            Bs[(k + 3) * 128 + lrow] = vb.w;
        }
        __syncthreads();
        #pragma unroll 4
        for (int kk = 0; kk < 32; kk++) {
            float4 a0 = *(const float4*)&As[kk * 128 + ty * 8];
            float4 a1 = *(const float4*)&As[kk * 128 + ty * 8 + 4];
            float4 b0 = *(const float4*)&Bs[kk * 128 + tx * 8];
            float4 b1 = *(const float4*)&Bs[kk * 128 + tx * 8 + 4];
            float av[8] = {a0.x, a0.y, a0.z, a0.w, a1.x, a1.y, a1.z, a1.w};
            float bv[8] = {b0.x, b0.y, b0.z, b0.w, b1.x, b1.y, b1.z, b1.w};
            #pragma unroll
            for (int r = 0; r < 8; r++)
                #pragma unroll
                for (int c = 0; c < 8; c++)
                    acc[r][c] += av[r] * bv[c];
        }
        __syncthreads();
    }

    int col = col0 + tx * 8;
    float gg[8], bbv[8], mm[8], rs[8], wb[8];
    #pragma unroll
    for (int h = 0; h < 2; h++) {
        float4 g4  = *(const float4*)(g_h  + col + h * 4);
        float4 b4  = *(const float4*)(b_h  + col + h * 4);
        float4 mu4 = *(const float4*)(mu_h + col + h * 4);
        float4 va4 = *(const float4*)(var_h + col + h * 4);
        float4 wb4 = *(const float4*)(Wb   + col + h * 4);
        gg[h*4+0]=g4.x; gg[h*4+1]=g4.y; gg[h*4+2]=g4.z; gg[h*4+3]=g4.w;
        bbv[h*4+0]=b4.x; bbv[h*4+1]=b4.y; bbv[h*4+2]=b4.z; bbv[h*4+3]=b4.w;
        mm[h*4+0]=mu4.x; mm[h*4+1]=mu4.y; mm[h*4+2]=mu4.z; mm[h*4+3]=mu4.w;
        rs[h*4+0]=1.0f/sqrtf(va4.x+EPS_); rs[h*4+1]=1.0f/sqrtf(va4.y+EPS_);
        rs[h*4+2]=1.0f/sqrtf(va4.z+EPS_); rs[h*4+3]=1.0f/sqrtf(va4.w+EPS_);
        wb[h*4+0]=wb4.x; wb[h*4+1]=wb4.y; wb[h*4+2]=wb4.z; wb[h*4+3]=wb4.w;
    }
    #pragma unroll
    for (int r = 0; r < 8; r++) {
        int row = row0 + ty * 8 + r;
        float o[8];
        #pragma unroll
        for (int j = 0; j < 8; j++)
            o[j] = gg[j] * ((acc[r][j] + wb[j]) - mm[j]) * rs[j] + bbv[j];
        float4 o0 = {o[0], o[1], o[2], o[3]};
        float4 o1 = {o[4], o[5], o[6], o[7]};
        *(float4*)(h_bn + (size_t)row * HD_ + col)     = o0;
        *(float4*)(h_bn + (size_t)row * HD_ + col + 4) = o1;
    }
}

// ---------------------------------------------------------------- K7: h-LIF (chunk 256, warm-up 128) -> out
__global__ __launch_bounds__(256) void k_hlif(const float* __restrict__ h_bn,
                                              float* __restrict__ out) {
    int b = blockIdx.x;
    int j = blockIdx.y * 64 + threadIdx.x;
    int c = blockIdx.z * 4 + threadIdx.y;        // 0..15
    int t0 = c * 256;
    int start = t0 - 128; if (start < 0) start = 0;
    float* hn = out + (size_t)B_ * S_ * HD_;
    float v = 0.f;
    for (int t = start; t < t0 + 256; t++) {
        float xv = h_bn[((size_t)b * S_ + t) * HD_ + j];
        v = v + (xv - v) * 0.5f;
        float sp = (v - 1.0f) >= 0.0f ? 1.0f : 0.0f;
        if (t >= t0) {
            out[((size_t)b * S_ + t) * HD_ + j] = sp;
            if (t == S_ - 1) hn[(size_t)b * HD_ + j] = sp;
        }
        v = v * (1.0f - sp);
    }
}

// ---------------------------------------------------------------- launch
extern "C" void kernel_launch(void* const* d_in, const int* in_sizes, int n_in,
                              void* d_out, int out_size, void* d_ws, size_t ws_size,
                              hipStream_t stream) {
    const float* x     = (const float*)d_in[0];
    const float* H     = (const float*)d_in[1];
    const float* Wu    = (const float*)d_in[2];
    const float* Wub   = (const float*)d_in[3];
    const float* Wh    = (const float*)d_in[4];
    const float* Whb   = (const float*)d_in[5];
    const float* g_u   = (const float*)d_in[6];
    const float* b_u   = (const float*)d_in[7];
    const float* mu_u  = (const float*)d_in[8];
    const float* var_u = (const float*)d_in[9];
    const float* g_m   = (const float*)d_in[10];
    const float* b_m   = (const float*)d_in[11];
    const float* mu_m  = (const float*)d_in[12];
    const float* var_m = (const float*)d_in[13];
    const float* g_h   = (const float*)d_in[14];
    const float* b_h   = (const float*)d_in[15];
    const float* mu_h  = (const float*)d_in[16];
    const float* var_h = (const float*)d_in[17];

    float* ws    = (float*)d_ws;
    float* u_bn  = ws;                               // 65536
    float* u_spk = ws + 65536;                       // 65536
    int*   spk_idx = (int*)(ws + 131072);            // 65536 ints
    int*   spk_cnt = (int*)(ws + 196608);            // 16 ints
    float* m_bn  = ws + 200704;                      // 16777216  [B,M,S]
    float* m_s   = m_bn + 16777216;                  // 16777216  [B,S,M]
    float* h_bn  = m_s + 16777216;                   // 25165824  [B*S,HD]

    k_upre<<<dim3(256), dim3(256), 0, stream>>>(x, Wu, Wub, g_u, b_u, mu_u, var_u, u_bn);
    k_ulif<<<dim3(16, 4), dim3(256), 0, stream>>>(u_bn, u_spk);
    k_compact<<<dim3(16), dim3(256), 0, stream>>>(u_spk, spk_idx, spk_cnt);
    k_conv<<<dim3(4096), dim3(256), 0, stream>>>(H, spk_idx, spk_cnt,
                                                 g_m, b_m, mu_m, var_m, m_bn);
    k_mlif<<<dim3(16, 4, 4), dim3(64, 4), 0, stream>>>(m_bn, m_s);
    k_hgemm<<<dim3(512, 3), dim3(256), 0, stream>>>(m_s, x, Wh, Whb,
                                                    g_h, b_h, mu_h, var_h, h_bn);
    k_hlif<<<dim3(16, 6, 4), dim3(64, 4), 0, stream>>>(h_bn, (float*)d_out);
}